// Round 6
// baseline (348.173 us; speedup 1.0000x reference)
//
#include <hip/hip_runtime.h>

// QINCoStep — bs=2048, d=128, K=256, h=256, fp32 in/out.
// Round 6: 256 cols per wg (grid 2048, 1 b per wg), selection fused into
// k_dist, atomicMin winner pick in k_exact, fused/coalesced prep kernels.
//
// ws layout (floats):
//   0 WzT 16384 | 16384 WxT 16384 | 32768 W1T0 32768 | 65536 W2T0 32768
//   98304 W1T1 32768 | 131072 W2T1 32768 | 163840 z0 32768 | 196608 u 262144
//   458752 z0bf(us 32768) | 475136 ubf(us 262144) | 606208 U1bf(us 524288)
//   868352 H1f(us 65536) | 901120 F(12288 uint4) | 950272 cand_k(int 16384)
//   966656 pairs(int2 16384) | 999424 npairs(int) | 999428 packed(ull 2048)

typedef short bf8_t __attribute__((ext_vector_type(8)));
typedef float f32x16 __attribute__((ext_vector_type(16)));

__device__ inline unsigned short f2bh(float x) {   // RNE f32->bf16
    unsigned u = __float_as_uint(x);
    u += 0x7fffu + ((u >> 16) & 1u);
    return (unsigned short)(u >> 16);
}
__device__ inline float bh2f(unsigned short h) {
    return __uint_as_float(((unsigned)h) << 16);
}
__device__ inline f32x16 mfma_bf(uint4 a, uint4 b, f32x16 c) {
    bf8_t av = __builtin_bit_cast(bf8_t, a);
    bf8_t bv = __builtin_bit_cast(bf8_t, b);
    return __builtin_amdgcn_mfma_f32_32x32x16_bf16(av, bv, c, 0, 0, 0);
}
__device__ inline unsigned addrelu2(unsigned hv, unsigned uv) {
    float h0 = __uint_as_float(hv << 16), h1 = __uint_as_float(hv & 0xFFFF0000u);
    float u0 = __uint_as_float(uv << 16), u1 = __uint_as_float(uv & 0xFFFF0000u);
    float v0 = fmaxf(h0 + u0, 0.f), v1 = fmaxf(h1 + u1, 0.f);
    return ((unsigned)f2bh(v1) << 16) | (unsigned)f2bh(v0);
}
__device__ inline unsigned pack2(float a, float b) {
    return ((unsigned)f2bh(b) << 16) | (unsigned)f2bh(a);
}

#define DELTA 4.0f

// ---------------- prep: transpose + frag pack (one kernel) ----------------
__global__ __launch_bounds__(256) void k_prep1(
    const float* __restrict__ Wc,
    const float* __restrict__ W1a, const float* __restrict__ W2a,
    const float* __restrict__ W1b, const float* __restrict__ W2b,
    float* __restrict__ WzT, float* __restrict__ WxT,
    float* __restrict__ W1Ta, float* __restrict__ W2Ta,
    float* __restrict__ W1Tb, float* __restrict__ W2Tb,
    uint4* __restrict__ F)
{
    int g = blockIdx.x * 256 + threadIdx.x;
    if (g < 16384) {
        int j = g >> 7, d = g & 127;
        WzT[g] = Wc[d * 256 + j];
    } else if (g < 32768) {
        int e = g - 16384; int j = e >> 7, d = e & 127;
        WxT[e] = Wc[d * 256 + 128 + j];
    } else if (g < 65536) {
        int e = g - 32768; int d = e >> 8, h = e & 255;
        W1Ta[e] = W1a[h * 128 + d];
    } else if (g < 98304) {
        int e = g - 65536; int h = e >> 7, i = e & 127;
        W2Ta[e] = W2a[i * 256 + h];
    } else if (g < 131072) {
        int e = g - 98304; int d = e >> 8, h = e & 255;
        W1Tb[e] = W1b[h * 128 + d];
    } else if (g < 163840) {
        int e = g - 131072; int h = e >> 7, i = e & 127;
        W2Tb[e] = W2b[i * 256 + h];
    } else if (g < 176128) {   // pack: 12288 frag-lane slots
        int idx = g - 163840;
        int mat = idx >> 12, fp = idx & 4095;
        int tile = fp >> 6, lane = fp & 63;
        const float* src;
        if (mat == 1) {            // W1_1: [256][128], 8mt x 8kt
            int mt = tile >> 3, kt = tile & 7;
            src = W1b + (32 * mt + (lane & 31)) * 128 + 16 * kt + 8 * (lane >> 5);
        } else {                   // W2-type: [128][256], 4mt x 16kt
            const float* W = (mat == 0) ? W2a : W2b;
            int mt = tile >> 4, kt = tile & 15;
            src = W + (32 * mt + (lane & 31)) * 256 + 16 * kt + 8 * (lane >> 5);
        }
        unsigned short hs[8];
#pragma unroll
        for (int j = 0; j < 8; ++j) hs[j] = f2bh(src[j]);
        uint4 hv;
        hv.x = (unsigned)hs[0] | ((unsigned)hs[1] << 16);
        hv.y = (unsigned)hs[2] | ((unsigned)hs[3] << 16);
        hv.z = (unsigned)hs[4] | ((unsigned)hs[5] << 16);
        hv.w = (unsigned)hs[6] | ((unsigned)hs[7] << 16);
        F[idx] = hv;
    }
}

// ---------------- prep: z0 + H1pre frags (4 k-rows per wg) ----------------
__global__ __launch_bounds__(256) void k_prep_k(
    const float* __restrict__ cb, const float* __restrict__ bc,
    const float* __restrict__ WzT, const float* __restrict__ W1T0,
    float* __restrict__ z0, unsigned short* __restrict__ z0bf,
    unsigned short* __restrict__ H1f)
{
    __shared__ float clds[4][128];
    __shared__ float zlds[4][128];
    const int t = threadIdx.x;
    const int r0 = blockIdx.x * 4;
#pragma unroll
    for (int e = t; e < 512; e += 256)
        clds[e >> 7][e & 127] = cb[(r0 + (e >> 7)) * 128 + (e & 127)];
    __syncthreads();
    {
        const int d = t & 127, r = t >> 7;   // r in 0..1 -> rows r, r+2
        float a0 = bc[d] + clds[r][d], a1 = bc[d] + clds[r + 2][d];
        for (int j = 0; j < 128; ++j) {
            const float w = WzT[j * 128 + d];
            a0 = fmaf(clds[r][j], w, a0);
            a1 = fmaf(clds[r + 2][j], w, a1);
        }
        z0[(r0 + r) * 128 + d] = a0;  z0bf[(r0 + r) * 128 + d] = f2bh(a0);
        z0[(r0 + r + 2) * 128 + d] = a1;  z0bf[(r0 + r + 2) * 128 + d] = f2bh(a1);
        zlds[r][d] = a0; zlds[r + 2][d] = a1;
    }
    __syncthreads();
    {   // t = h
        float a[4] = {0.f, 0.f, 0.f, 0.f};
        for (int d = 0; d < 128; ++d) {
            const float w = W1T0[d * 256 + t];   // coalesced
#pragma unroll
            for (int r = 0; r < 4; ++r) a[r] = fmaf(zlds[r][d], w, a[r]);
        }
        const int kt = t >> 4, half = (t >> 3) & 1, j = t & 7;
#pragma unroll
        for (int r = 0; r < 4; ++r) {
            int k = r0 + r; int kg = k >> 5, col = k & 31;
            H1f[(((kg * 16 + kt) * 64) + half * 32 + col) * 8 + j] = f2bh(a[r]);
        }
    }
}

// ---------------- prep: u + U1bf (4 b-rows per wg) ----------------
__global__ __launch_bounds__(256) void k_prep_b(
    const float* __restrict__ xhat, const float* __restrict__ WxT,
    const float* __restrict__ W1T0,
    float* __restrict__ u, unsigned short* __restrict__ ubf,
    unsigned short* __restrict__ U1bf)
{
    __shared__ float xlds[4][128];
    __shared__ float ulds[4][128];
    const int t = threadIdx.x;
    const int r0 = blockIdx.x * 4;
#pragma unroll
    for (int e = t; e < 512; e += 256)
        xlds[e >> 7][e & 127] = xhat[(r0 + (e >> 7)) * 128 + (e & 127)];
    __syncthreads();
    {
        const int d = t & 127, r = t >> 7;
        float a0 = 0.f, a1 = 0.f;
        for (int j = 0; j < 128; ++j) {
            const float w = WxT[j * 128 + d];
            a0 = fmaf(xlds[r][j], w, a0);
            a1 = fmaf(xlds[r + 2][j], w, a1);
        }
        u[(r0 + r) * 128 + d] = a0;  ubf[(r0 + r) * 128 + d] = f2bh(a0);
        u[(r0 + r + 2) * 128 + d] = a1;  ubf[(r0 + r + 2) * 128 + d] = f2bh(a1);
        ulds[r][d] = a0; ulds[r + 2][d] = a1;
    }
    __syncthreads();
    {
        float a[4] = {0.f, 0.f, 0.f, 0.f};
        for (int d = 0; d < 128; ++d) {
            const float w = W1T0[d * 256 + t];   // coalesced
#pragma unroll
            for (int r = 0; r < 4; ++r) a[r] = fmaf(ulds[r][d], w, a[r]);
        }
#pragma unroll
        for (int r = 0; r < 4; ++r)
            U1bf[(r0 + r) * 256 + t] = f2bh(a[r]);
    }
}

// ---------------- main: approx dist + fused select ----------------
// grid 2048 (wg = one b, all 256 codes), 512 thr / 8 waves.
// wave -> (wm = wave&3: d-tile, wn = wave>>2). zs[4]: colgroups {4wn+g}.
__global__ __launch_bounds__(512) void k_dist_approx(
    const unsigned short* __restrict__ z0bf, const unsigned short* __restrict__ ubf,
    const float* __restrict__ xhat, const float* __restrict__ x,
    const uint4* __restrict__ H1f, const unsigned short* __restrict__ U1bf,
    const uint4* __restrict__ W2f0, const uint4* __restrict__ W1f1,
    const uint4* __restrict__ W2f1,
    int* __restrict__ cand_k, int2* __restrict__ pairs, int* __restrict__ npairs)
{
    __shared__ uint4 Zf[4096];   // 64 KB: blocks (cg*8 + kt), cg 0..7
    __shared__ uint4 Hf[2048];   // 32 KB: blocks (cg*4 + ktl); tail reused for red/sdist/sk

    const int t = threadIdx.x;
    const int lane = t & 63, wave = t >> 6;
    const int wm = wave & 3, wn = wave >> 2;
    const int l31 = lane & 31, l5 = lane >> 5;
    const int b = blockIdx.x;

    // init zs = bf(z0[k]) + bf(u[b]) at C-frag positions (d = 32wm+8rg+4l5+j)
    f32x16 zs[4];
    {
        const unsigned short* ur = ubf + b * 128;
#pragma unroll
        for (int g = 0; g < 4; ++g) {
            const int col = ((wn << 2) + g) * 32 + l31;
            const unsigned short* zr = z0bf + col * 128;
#pragma unroll
            for (int rg = 0; rg < 4; ++rg) {
                const int d0 = 32 * wm + 8 * rg + 4 * l5;
                ushort4 a = *(const ushort4*)(zr + d0);
                ushort4 c = *(const ushort4*)(ur + d0);
                zs[g][4*rg+0] = bh2f(a.x) + bh2f(c.x);
                zs[g][4*rg+1] = bh2f(a.y) + bh2f(c.y);
                zs[g][4*rg+2] = bh2f(a.z) + bh2f(c.z);
                zs[g][4*rg+3] = bh2f(a.w) + bh2f(c.w);
            }
        }
    }

    // P0: blk0-G2: zs += W2_0 . relu(H1pre[k]+U1[b])^T, 4 rounds of 4 kt
#pragma unroll 1
    for (int r = 0; r < 4; ++r) {
        {   // stage r0 frags: wave covers kt = 4r+wm, cgs {4wn..4wn+3}
            const int kt = 4 * r + wm;
            const uint4 uv = *(const uint4*)(U1bf + b * 256 + kt * 16 + 8 * l5);
#pragma unroll
            for (int gi = 0; gi < 4; ++gi) {
                const int cg = (wn << 2) + gi;
                uint4 hv = H1f[((cg << 4) + kt) * 64 + lane];
                uint4 o;
                o.x = addrelu2(hv.x, uv.x);
                o.y = addrelu2(hv.y, uv.y);
                o.z = addrelu2(hv.z, uv.z);
                o.w = addrelu2(hv.w, uv.w);
                Hf[((cg << 2) + wm) * 64 + lane] = o;
            }
        }
        __syncthreads();
#pragma unroll
        for (int ktl = 0; ktl < 4; ++ktl) {
            uint4 ah = W2f0[((wm << 4) + 4 * r + ktl) * 64 + lane];
#pragma unroll
            for (int g = 0; g < 4; ++g) {
                uint4 bv = Hf[((((wn << 2) + g) << 2) + ktl) * 64 + lane];
                zs[g] = mfma_bf(ah, bv, zs[g]);
            }
        }
        __syncthreads();
    }

    // P1: write z1 (bf16) to Zf in B-frag order
#pragma unroll
    for (int g = 0; g < 4; ++g) {
        const int cg = (wn << 2) + g;
#pragma unroll
        for (int rg = 0; rg < 4; ++rg) {
            uint2 hv;
            hv.x = pack2(zs[g][4*rg+0], zs[g][4*rg+1]);
            hv.y = pack2(zs[g][4*rg+2], zs[g][4*rg+3]);
            uint2* zb2 = (uint2*)&Zf[((cg << 3) + 2 * wm + (rg >> 1)) * 64];
            zb2[(((rg & 1) << 5) + l31) * 2 + l5] = hv;
        }
    }
    __syncthreads();

    // P2: blk1, 4 chunks of 64 h.
    // G1: wave -> tile = wn (h-tile within chunk), cgs {2wm, 2wm+1}.
#pragma unroll 1
    for (int c = 0; c < 4; ++c) {
        f32x16 a0, a1;
#pragma unroll
        for (int rr = 0; rr < 16; ++rr) { a0[rr] = 0.f; a1[rr] = 0.f; }
        {
            const uint4* pw1 = W1f1 + ((2 * c + wn) << 3) * 64;
#pragma unroll
            for (int kt = 0; kt < 8; ++kt) {
                uint4 ah = pw1[kt * 64 + lane];
                uint4 b0 = Zf[(((2 * wm) << 3) + kt) * 64 + lane];
                uint4 b1 = Zf[(((2 * wm + 1) << 3) + kt) * 64 + lane];
                a0 = mfma_bf(ah, b0, a0);
                a1 = mfma_bf(ah, b1, a1);
            }
        }
        __syncthreads();   // G2(c-1) / P0 readers done before Hf overwrite
#pragma unroll
        for (int rg = 0; rg < 4; ++rg) {
            const int ktl = (wn << 1) + (rg >> 1);
            const int sl = (((rg & 1) << 5) + l31) * 2 + l5;
            uint2 hv;
            hv.x = pack2(fmaxf(a0[4*rg+0], 0.f), fmaxf(a0[4*rg+1], 0.f));
            hv.y = pack2(fmaxf(a0[4*rg+2], 0.f), fmaxf(a0[4*rg+3], 0.f));
            ((uint2*)&Hf[(((2 * wm) << 2) + ktl) * 64])[sl] = hv;
            hv.x = pack2(fmaxf(a1[4*rg+0], 0.f), fmaxf(a1[4*rg+1], 0.f));
            hv.y = pack2(fmaxf(a1[4*rg+2], 0.f), fmaxf(a1[4*rg+3], 0.f));
            ((uint2*)&Hf[(((2 * wm + 1) << 2) + ktl) * 64])[sl] = hv;
        }
        __syncthreads();
#pragma unroll
        for (int ktl = 0; ktl < 4; ++ktl) {
            uint4 ah = W2f1[((wm << 4) + 4 * c + ktl) * 64 + lane];
#pragma unroll
            for (int g = 0; g < 4; ++g) {
                uint4 bv = Hf[((((wn << 2) + g) << 2) + ktl) * 64 + lane];
                zs[g] = mfma_bf(ah, bv, zs[g]);
            }
        }
    }

    // P3: dist + fused candidate selection
    float* red   = (float*)Hf;          // [4][256]
    float* sdist = (float*)Hf + 1024;   // [256]
    int*   sk    = (int*)((float*)Hf + 1280);   // [8]
    __syncthreads();   // all Hf MFMA readers done
#pragma unroll
    for (int g = 0; g < 4; ++g) {
        float s = 0.f;
        const int col = ((wn << 2) + g) * 32 + l31;
#pragma unroll
        for (int rg = 0; rg < 4; ++rg) {
            const int d0 = 32 * wm + 8 * rg + 4 * l5;
            float4 xh = *(const float4*)(xhat + b * 128 + d0);
            float4 xx = *(const float4*)(x + b * 128 + d0);
            float v;
            v = zs[g][4*rg+0] + xh.x - xx.x; s = fmaf(v, v, s);
            v = zs[g][4*rg+1] + xh.y - xx.y; s = fmaf(v, v, s);
            v = zs[g][4*rg+2] + xh.z - xx.z; s = fmaf(v, v, s);
            v = zs[g][4*rg+3] + xh.w - xx.w; s = fmaf(v, v, s);
        }
        s += __shfl_xor(s, 32, 64);
        if (l5 == 0) red[wm * 256 + col] = s;
    }
    __syncthreads();
    if (t < 256)
        sdist[t] = red[t] + red[256 + t] + red[512 + t] + red[768 + t];
    __syncthreads();
    int base = 0;
    if (wave == 0) {
        float v[4];
#pragma unroll
        for (int j = 0; j < 4; ++j) v[j] = sdist[lane + 64 * j];
        float m = fminf(fminf(v[0], v[1]), fminf(v[2], v[3]));
#pragma unroll
        for (int off = 32; off > 0; off >>= 1) m = fminf(m, __shfl_xor(m, off, 64));
        const float thr = m + DELTA;
        const unsigned long long below = (1ull << lane) - 1;
#pragma unroll
        for (int j = 0; j < 4; ++j) {
            bool p = v[j] <= thr;
            unsigned long long mask = __ballot(p);
            int pos = base + __popcll(mask & below);
            if (p && pos < 8) sk[pos] = 64 * j + lane;
            base += __popcll(mask);
        }
    }
    __syncthreads();
    if (t == 0) {
        int c = base > 8 ? 8 : base;
        int off = atomicAdd(npairs, c);
        for (int s = 0; s < c; ++s) {
            int kk = sk[s];
            cand_k[b * 8 + s] = kk;
            pairs[off + s] = make_int2(b, (kk << 4) | s);
        }
    }
}

// ---------------- exact f32 candidate dists + atomicMin winner ----------------
__global__ __launch_bounds__(256) void k_exact(
    const float* __restrict__ z0, const float* __restrict__ u,
    const float* __restrict__ xhat, const float* __restrict__ x,
    const int2* __restrict__ pairs, const int* __restrict__ npairs,
    const float* __restrict__ W1Ta, const float* __restrict__ W2Ta,
    const float* __restrict__ W1Tb, const float* __restrict__ W2Tb,
    unsigned long long* __restrict__ packed)
{
    __shared__ float z8[8][128];
    __shared__ float h8[8][256];
    __shared__ int pb[8], pk[8], psl[8];
    __shared__ int scnt;
    __shared__ float part[8][32];
    const int t = threadIdx.x;
    if (t == 0) {
        int np = *npairs; if (np > 16384) np = 16384;
        int c = np - (int)blockIdx.x * 8;
        scnt = c < 0 ? 0 : (c > 8 ? 8 : c);
    }
    __syncthreads();
    const int cnt = scnt;
    if (cnt == 0) return;
    if (t < 8) {
        int idx = blockIdx.x * 8 + (t < cnt ? t : cnt - 1);
        int2 p = pairs[idx];
        pb[t] = p.x; pk[t] = p.y >> 4; psl[t] = p.y & 15;
    }
    __syncthreads();
#pragma unroll
    for (int n = 0; n < 4; ++n) {
        int e = n * 256 + t; int r = e >> 7, d = e & 127;
        z8[r][d] = z0[pk[r] * 128 + d] + u[pb[r] * 128 + d];
    }
    __syncthreads();
    const float* W1T = W1Ta; const float* W2T = W2Ta;
#pragma unroll 1
    for (int blk = 0; blk < 2; ++blk) {
        float a1[8] = {0.f,0.f,0.f,0.f,0.f,0.f,0.f,0.f};
        for (int d = 0; d < 128; ++d) {
            const float w = W1T[d * 256 + t];
#pragma unroll
            for (int r = 0; r < 8; ++r) a1[r] = fmaf(z8[r][d], w, a1[r]);
        }
#pragma unroll
        for (int r = 0; r < 8; ++r) h8[r][t] = fmaxf(a1[r], 0.f);
        __syncthreads();
        const int ig = t & 127, rg = (t >> 7) * 4;
        float a2[4] = {0.f,0.f,0.f,0.f};
        for (int h = 0; h < 256; ++h) {
            const float w = W2T[h * 128 + ig];
#pragma unroll
            for (int j = 0; j < 4; ++j) a2[j] = fmaf(h8[rg + j][h], w, a2[j]);
        }
        __syncthreads();
#pragma unroll
        for (int j = 0; j < 4; ++j) z8[rg + j][ig] += a2[j];
        __syncthreads();
        W1T = W1Tb; W2T = W2Tb;
    }
    {
        const int r = t >> 5, c = t & 31;
        const int br = pb[r];
        float s = 0.f;
#pragma unroll
        for (int i = 0; i < 4; ++i) {
            int d = c * 4 + i;
            float v = z8[r][d] + xhat[br * 128 + d] - x[br * 128 + d];
            s = fmaf(v, v, s);
        }
        part[r][c] = s;
    }
    __syncthreads();
    if (t < 8 && t < cnt) {
        float s = 0.f;
#pragma unroll
        for (int c2 = 0; c2 < 32; ++c2) s += part[t][c2];
        unsigned long long pk64 = (((unsigned long long)__float_as_uint(s)) << 8)
                                | (unsigned long long)psl[t];
        atomicMin(&packed[pb[t]], pk64);
    }
}

// ---------------- winner recompute + output (f32-exact) ----------------
__global__ __launch_bounds__(256) void k_final(
    const float* __restrict__ z0, const float* __restrict__ u,
    const unsigned long long* __restrict__ packed, const int* __restrict__ cand_k,
    const float* __restrict__ W1Ta, const float* __restrict__ W2Ta,
    const float* __restrict__ W1Tb, const float* __restrict__ W2Tb,
    float* __restrict__ out0, float* __restrict__ outd)
{
    __shared__ float z8[8][128];
    __shared__ float h8[8][256];
    __shared__ int ci[8];
    const int t = threadIdx.x;
    const int b0 = blockIdx.x * 8;
    if (t < 8) {
        int slot = (int)(packed[b0 + t] & 0xFFull);
        int code = cand_k[(b0 + t) * 8 + slot];
        ci[t] = code;
        out0[b0 + t] = (float)code;
    }
    __syncthreads();
#pragma unroll
    for (int n = 0; n < 4; ++n) {
        int e = n * 256 + t; int r = e >> 7, d = e & 127;
        z8[r][d] = z0[ci[r] * 128 + d] + u[(b0 + r) * 128 + d];
    }
    __syncthreads();
    const float* W1T = W1Ta; const float* W2T = W2Ta;
#pragma unroll 1
    for (int blk = 0; blk < 2; ++blk) {
        float a1[8] = {0.f,0.f,0.f,0.f,0.f,0.f,0.f,0.f};
        for (int d = 0; d < 128; ++d) {
            const float w = W1T[d * 256 + t];
#pragma unroll
            for (int r = 0; r < 8; ++r) a1[r] = fmaf(z8[r][d], w, a1[r]);
        }
#pragma unroll
        for (int r = 0; r < 8; ++r) h8[r][t] = fmaxf(a1[r], 0.f);
        __syncthreads();
        const int ig = t & 127, rg = (t >> 7) * 4;
        float a2[4] = {0.f,0.f,0.f,0.f};
        for (int h = 0; h < 256; ++h) {
            const float w = W2T[h * 128 + ig];
#pragma unroll
            for (int j = 0; j < 4; ++j) a2[j] = fmaf(h8[rg + j][h], w, a2[j]);
        }
        __syncthreads();
#pragma unroll
        for (int j = 0; j < 4; ++j) z8[rg + j][ig] += a2[j];
        __syncthreads();
        W1T = W1Tb; W2T = W2Tb;
    }
#pragma unroll
    for (int n = 0; n < 4; ++n) {
        int e = n * 256 + t; int r = e >> 7, d = e & 127;
        outd[(b0 + r) * 128 + d] = z8[r][d];
    }
}

extern "C" void kernel_launch(void* const* d_in, const int* in_sizes, int n_in,
                              void* d_out, int out_size, void* d_ws, size_t ws_size,
                              hipStream_t stream) {
    const float* xhat = (const float*)d_in[0];
    const float* x    = (const float*)d_in[1];
    const float* cb   = (const float*)d_in[2];
    const float* Wc   = (const float*)d_in[3];
    const float* bc   = (const float*)d_in[4];
    const float* W1_0 = (const float*)d_in[5];
    const float* W2_0 = (const float*)d_in[6];
    const float* W1_1 = (const float*)d_in[7];
    const float* W2_1 = (const float*)d_in[8];
    float* out = (float*)d_out;
    float* ws  = (float*)d_ws;

    float* WzT   = ws + 0;
    float* WxT   = ws + 16384;
    float* W1T0  = ws + 32768;
    float* W2T0  = ws + 65536;
    float* W1T1  = ws + 98304;
    float* W2T1  = ws + 131072;
    float* z0    = ws + 163840;
    float* u     = ws + 196608;
    unsigned short* z0bf = (unsigned short*)(ws + 458752);
    unsigned short* ubf  = (unsigned short*)(ws + 475136);
    unsigned short* U1bf = (unsigned short*)(ws + 606208);
    unsigned short* H1f  = (unsigned short*)(ws + 868352);
    uint4* F     = (uint4*)(ws + 901120);
    const uint4* W2f0 = F;
    const uint4* W1f1 = F + 4096;
    const uint4* W2f1 = F + 8192;
    int*   cand_k = (int*)(ws + 950272);
    int2*  pairs  = (int2*)(ws + 966656);
    int*   npairs = (int*)(ws + 999424);
    unsigned long long* packed = (unsigned long long*)(ws + 999428);

    k_prep1<<<688, 256, 0, stream>>>(Wc, W1_0, W2_0, W1_1, W2_1,
                                     WzT, WxT, W1T0, W2T0, W1T1, W2T1, F);
    k_prep_k<<<64, 256, 0, stream>>>(cb, bc, WzT, W1T0, z0, z0bf, H1f);
    k_prep_b<<<512, 256, 0, stream>>>(xhat, WxT, W1T0, u, ubf, U1bf);
    hipMemsetAsync(npairs, 0, 4, stream);
    hipMemsetAsync(packed, 0xFF, 2048 * 8, stream);
    k_dist_approx<<<2048, 512, 0, stream>>>(z0bf, ubf, xhat, x, (const uint4*)H1f,
                                            U1bf, W2f0, W1f1, W2f1,
                                            cand_k, pairs, npairs);
    k_exact<<<2048, 256, 0, stream>>>(z0, u, xhat, x, pairs, npairs,
                                      W1T0, W2T0, W1T1, W2T1, packed);
    k_final<<<256, 256, 0, stream>>>(z0, u, packed, cand_k,
                                     W1T0, W2T0, W1T1, W2T1, out, out + 2048);
}

// Round 7
// 322.270 us; speedup vs baseline: 1.0804x; 1.0804x over previous
//
#include <hip/hip_runtime.h>

// QINCoStep — bs=2048, d=128, K=256, h=256, fp32 in/out.
// Round 7: R5 structure (128 cols/wg, 48KB LDS, 3 wg/CU) + f32 staging
// sources + truncation v_perm packs (VALU cut) + fused select + atomicMin
// winner pick. DELTA=6 covers truncation error (exact pass refines).
//
// ws layout (floats):
//   0 WzT 16384 | 16384 WxT 16384 | 32768 W1T0 32768 | 65536 W2T0 32768
//   98304 W1T1 32768 | 131072 W2T1 32768 | 163840 z0 32768 | 196608 u 262144
//   458752 H1f32 65536 (frag-ordered) | 524288 U1 524288
//   1048576 F (12288 uint4) | 1097728 pairs (int2 32768)
//   1163264 npairs | 1163268 packed (ull 2048)

typedef short bf8_t __attribute__((ext_vector_type(8)));
typedef float f32x16 __attribute__((ext_vector_type(16)));

__device__ inline unsigned short f2bh(float x) {   // RNE f32->bf16 (prep only)
    unsigned u = __float_as_uint(x);
    u += 0x7fffu + ((u >> 16) & 1u);
    return (unsigned short)(u >> 16);
}
__device__ inline f32x16 mfma_bf(uint4 a, uint4 b, f32x16 c) {
    bf8_t av = __builtin_bit_cast(bf8_t, a);
    bf8_t bv = __builtin_bit_cast(bf8_t, b);
    return __builtin_amdgcn_mfma_f32_32x32x16_bf16(av, bv, c, 0, 0, 0);
}
// truncation pack: hi16(x) low, hi16(y) high — 1 v_perm_b32
__device__ inline unsigned packhi(float x, float y) {
    return __builtin_amdgcn_perm(__float_as_uint(y), __float_as_uint(x), 0x07060302u);
}

#define DELTA 6.0f

// ---------------- prep: transpose + frag pack ----------------
__global__ __launch_bounds__(256) void k_prep1(
    const float* __restrict__ Wc,
    const float* __restrict__ W1a, const float* __restrict__ W2a,
    const float* __restrict__ W1b, const float* __restrict__ W2b,
    float* __restrict__ WzT, float* __restrict__ WxT,
    float* __restrict__ W1Ta, float* __restrict__ W2Ta,
    float* __restrict__ W1Tb, float* __restrict__ W2Tb,
    uint4* __restrict__ F)
{
    int g = blockIdx.x * 256 + threadIdx.x;
    if (g < 16384) {
        int j = g >> 7, d = g & 127;
        WzT[g] = Wc[d * 256 + j];
    } else if (g < 32768) {
        int e = g - 16384; int j = e >> 7, d = e & 127;
        WxT[e] = Wc[d * 256 + 128 + j];
    } else if (g < 65536) {
        int e = g - 32768; int d = e >> 8, h = e & 255;
        W1Ta[e] = W1a[h * 128 + d];
    } else if (g < 98304) {
        int e = g - 65536; int h = e >> 7, i = e & 127;
        W2Ta[e] = W2a[i * 256 + h];
    } else if (g < 131072) {
        int e = g - 98304; int d = e >> 8, h = e & 255;
        W1Tb[e] = W1b[h * 128 + d];
    } else if (g < 163840) {
        int e = g - 131072; int h = e >> 7, i = e & 127;
        W2Tb[e] = W2b[i * 256 + h];
    } else if (g < 176128) {   // 12288 frag-lane slots (RNE, prep-time)
        int idx = g - 163840;
        int mat = idx >> 12, fp = idx & 4095;
        int tile = fp >> 6, lane = fp & 63;
        const float* src;
        if (mat == 1) {            // W1_1: [256][128], 8mt x 8kt
            int mt = tile >> 3, kt = tile & 7;
            src = W1b + (32 * mt + (lane & 31)) * 128 + 16 * kt + 8 * (lane >> 5);
        } else {                   // W2-type: [128][256], 4mt x 16kt
            const float* W = (mat == 0) ? W2a : W2b;
            int mt = tile >> 4, kt = tile & 15;
            src = W + (32 * mt + (lane & 31)) * 256 + 16 * kt + 8 * (lane >> 5);
        }
        unsigned short hs[8];
#pragma unroll
        for (int j = 0; j < 8; ++j) hs[j] = f2bh(src[j]);
        uint4 hv;
        hv.x = (unsigned)hs[0] | ((unsigned)hs[1] << 16);
        hv.y = (unsigned)hs[2] | ((unsigned)hs[3] << 16);
        hv.z = (unsigned)hs[4] | ((unsigned)hs[5] << 16);
        hv.w = (unsigned)hs[6] | ((unsigned)hs[7] << 16);
        F[idx] = hv;
    }
}

// ---------------- prep: z0 + H1pre (f32, frag-ordered) ----------------
__global__ __launch_bounds__(256) void k_prep_k(
    const float* __restrict__ cb, const float* __restrict__ bc,
    const float* __restrict__ WzT, const float* __restrict__ W1T0,
    float* __restrict__ z0, float* __restrict__ H1f32)
{
    __shared__ float clds[4][128];
    __shared__ float zlds[4][128];
    const int t = threadIdx.x;
    const int r0 = blockIdx.x * 4;
#pragma unroll
    for (int e = t; e < 512; e += 256)
        clds[e >> 7][e & 127] = cb[(r0 + (e >> 7)) * 128 + (e & 127)];
    __syncthreads();
    {
        const int d = t & 127, r = t >> 7;   // rows r, r+2
        float a0 = bc[d] + clds[r][d], a1 = bc[d] + clds[r + 2][d];
        for (int j = 0; j < 128; ++j) {
            const float w = WzT[j * 128 + d];
            a0 = fmaf(clds[r][j], w, a0);
            a1 = fmaf(clds[r + 2][j], w, a1);
        }
        z0[(r0 + r) * 128 + d] = a0;
        z0[(r0 + r + 2) * 128 + d] = a1;
        zlds[r][d] = a0; zlds[r + 2][d] = a1;
    }
    __syncthreads();
    {   // t = h
        float a[4] = {0.f, 0.f, 0.f, 0.f};
        for (int d = 0; d < 128; ++d) {
            const float w = W1T0[d * 256 + t];   // coalesced
#pragma unroll
            for (int r = 0; r < 4; ++r) a[r] = fmaf(zlds[r][d], w, a[r]);
        }
        const int kt = t >> 4, half = (t >> 3) & 1, j = t & 7;
#pragma unroll
        for (int r = 0; r < 4; ++r) {
            int k = r0 + r; int kg = k >> 5, col = k & 31;
            H1f32[(((kg * 16 + kt) * 64) + half * 32 + col) * 8 + j] = a[r];
        }
    }
}

// ---------------- prep: u + U1 (f32) ----------------
__global__ __launch_bounds__(256) void k_prep_b(
    const float* __restrict__ xhat, const float* __restrict__ WxT,
    const float* __restrict__ W1T0,
    float* __restrict__ u, float* __restrict__ U1)
{
    __shared__ float xlds[4][128];
    __shared__ float ulds[4][128];
    const int t = threadIdx.x;
    const int r0 = blockIdx.x * 4;
#pragma unroll
    for (int e = t; e < 512; e += 256)
        xlds[e >> 7][e & 127] = xhat[(r0 + (e >> 7)) * 128 + (e & 127)];
    __syncthreads();
    {
        const int d = t & 127, r = t >> 7;
        float a0 = 0.f, a1 = 0.f;
        for (int j = 0; j < 128; ++j) {
            const float w = WxT[j * 128 + d];
            a0 = fmaf(xlds[r][j], w, a0);
            a1 = fmaf(xlds[r + 2][j], w, a1);
        }
        u[(r0 + r) * 128 + d] = a0;
        u[(r0 + r + 2) * 128 + d] = a1;
        ulds[r][d] = a0; ulds[r + 2][d] = a1;
    }
    __syncthreads();
    {
        float a[4] = {0.f, 0.f, 0.f, 0.f};
        for (int d = 0; d < 128; ++d) {
            const float w = W1T0[d * 256 + t];   // coalesced
#pragma unroll
            for (int r = 0; r < 4; ++r) a[r] = fmaf(ulds[r][d], w, a[r]);
        }
#pragma unroll
        for (int r = 0; r < 4; ++r)
            U1[(r0 + r) * 256 + t] = a[r];
    }
}

// ---------------- main: approx dist + fused select ----------------
// 512 thr / 8 waves; wg = (b, 128-code half q). wave: wm=wave&3, wn=wave>>2.
// zs[2]: colgroups {2wn, 2wn+1} (local cg 0..3). Frag block = 64 uint4.
__global__ __launch_bounds__(512, 6) void k_dist_approx(
    const float* __restrict__ z0, const float* __restrict__ u,
    const float* __restrict__ xhat, const float* __restrict__ x,
    const float* __restrict__ H1f32, const float* __restrict__ U1,
    const uint4* __restrict__ W2f0, const uint4* __restrict__ W1f1,
    const uint4* __restrict__ W2f1,
    int2* __restrict__ pairs, int* __restrict__ npairs)
{
    __shared__ uint4 Zf[2048];   // 32 KB: blocks (cg*8 + kt)
    __shared__ uint4 Hf[1024];   // 16 KB: blocks (cg*4 + ktl); tail: red/sdist/sk

    const int t = threadIdx.x;
    const int lane = t & 63, wave = t >> 6;
    const int wm = wave & 3, wn = wave >> 2;
    const int l31 = lane & 31, l5 = lane >> 5;
    const int b = blockIdx.x >> 1, q = blockIdx.x & 1;
    const int k0 = q << 7;

    // init zs = z0[k] + u[b] (f32) at C-frag positions (d = 32wm+8rg+4l5+j)
    f32x16 zs[2];
    {
        const float* ur = u + b * 128;
#pragma unroll
        for (int g = 0; g < 2; ++g) {
            const int col = ((wn << 1) + g) * 32 + l31;
            const float* zr = z0 + (k0 + col) * 128;
#pragma unroll
            for (int rg = 0; rg < 4; ++rg) {
                const int d0 = 32 * wm + 8 * rg + 4 * l5;
                float4 a = *(const float4*)(zr + d0);
                float4 c = *(const float4*)(ur + d0);
                zs[g][4*rg+0] = a.x + c.x;
                zs[g][4*rg+1] = a.y + c.y;
                zs[g][4*rg+2] = a.z + c.z;
                zs[g][4*rg+3] = a.w + c.w;
            }
        }
    }

    // P0: blk0-G2: zs += W2_0 . relu(H1pre[k]+U1[b])^T, 4 rounds of 4 kt
#pragma unroll 1
    for (int r = 0; r < 4; ++r) {
        {   // stage: wave -> kt = 4r+wm, cgs {2wn, 2wn+1}
            const int kt = 4 * r + wm;
            const float4* up = (const float4*)(U1 + b * 256 + kt * 16 + 8 * l5);
            float4 ua = up[0], ub = up[1];
#pragma unroll
            for (int gi = 0; gi < 2; ++gi) {
                const int cg = (wn << 1) + gi;
                const int kg = (q << 2) + cg;
                const float4* hp = (const float4*)(H1f32 + (((kg * 16 + kt) * 64) + lane) * 8);
                float4 ha = hp[0], hb = hp[1];
                float v0 = fmaxf(ha.x + ua.x, 0.f), v1 = fmaxf(ha.y + ua.y, 0.f);
                float v2 = fmaxf(ha.z + ua.z, 0.f), v3 = fmaxf(ha.w + ua.w, 0.f);
                float v4 = fmaxf(hb.x + ub.x, 0.f), v5 = fmaxf(hb.y + ub.y, 0.f);
                float v6 = fmaxf(hb.z + ub.z, 0.f), v7 = fmaxf(hb.w + ub.w, 0.f);
                uint4 o;
                o.x = packhi(v0, v1); o.y = packhi(v2, v3);
                o.z = packhi(v4, v5); o.w = packhi(v6, v7);
                Hf[((cg << 2) + wm) * 64 + lane] = o;
            }
        }
        __syncthreads();
#pragma unroll
        for (int ktl = 0; ktl < 4; ++ktl) {
            uint4 ah = W2f0[((wm << 4) + 4 * r + ktl) * 64 + lane];
#pragma unroll
            for (int g = 0; g < 2; ++g) {
                uint4 bv = Hf[((((wn << 1) + g) << 2) + ktl) * 64 + lane];
                zs[g] = mfma_bf(ah, bv, zs[g]);
            }
        }
        __syncthreads();
    }

    // P1: write z1 (trunc bf16) to Zf in B-frag order
#pragma unroll
    for (int g = 0; g < 2; ++g) {
        const int cg = (wn << 1) + g;
#pragma unroll
        for (int rg = 0; rg < 4; ++rg) {
            uint2 hv;
            hv.x = packhi(zs[g][4*rg+0], zs[g][4*rg+1]);
            hv.y = packhi(zs[g][4*rg+2], zs[g][4*rg+3]);
            uint2* zb2 = (uint2*)&Zf[((cg << 3) + 2 * wm + (rg >> 1)) * 64];
            zb2[(((rg & 1) << 5) + l31) * 2 + l5] = hv;
        }
    }
    __syncthreads();

    // P2: blk1, 4 chunks of 64 h. G1: wave -> tile = wave&1, cg = wave>>1.
    const int tile = wave & 1, cg1 = wave >> 1;
#pragma unroll 1
    for (int c = 0; c < 4; ++c) {
        f32x16 acc;
#pragma unroll
        for (int rr = 0; rr < 16; ++rr) acc[rr] = 0.f;
        {
            const uint4* pw1 = W1f1 + ((2 * c + tile) << 3) * 64;
#pragma unroll
            for (int kt = 0; kt < 8; ++kt) {
                uint4 bv = Zf[((cg1 << 3) + kt) * 64 + lane];
                uint4 ah = pw1[kt * 64 + lane];
                acc = mfma_bf(ah, bv, acc);
            }
        }
        __syncthreads();   // previous chunk's Hf readers done
#pragma unroll
        for (int rg = 0; rg < 4; ++rg) {
            float v0 = fmaxf(acc[4*rg+0], 0.f), v1 = fmaxf(acc[4*rg+1], 0.f);
            float v2 = fmaxf(acc[4*rg+2], 0.f), v3 = fmaxf(acc[4*rg+3], 0.f);
            uint2 hv; hv.x = packhi(v0, v1); hv.y = packhi(v2, v3);
            uint2* hb2 = (uint2*)&Hf[((cg1 << 2) + (tile << 1) + (rg >> 1)) * 64];
            hb2[(((rg & 1) << 5) + l31) * 2 + l5] = hv;
        }
        __syncthreads();
#pragma unroll
        for (int ktl = 0; ktl < 4; ++ktl) {
            uint4 ah = W2f1[((wm << 4) + 4 * c + ktl) * 64 + lane];
#pragma unroll
            for (int g = 0; g < 2; ++g) {
                uint4 bv = Hf[((((wn << 1) + g) << 2) + ktl) * 64 + lane];
                zs[g] = mfma_bf(ah, bv, zs[g]);
            }
        }
    }

    // P3: dist + fused candidate selection (local half-min threshold)
    float* red   = (float*)Hf;          // [4][128]
    float* sdist = (float*)Hf + 512;    // [128]
    int*   sk    = (int*)((float*)Hf + 640);   // [8]
    __syncthreads();   // all Hf MFMA readers done
#pragma unroll
    for (int g = 0; g < 2; ++g) {
        float s = 0.f;
        const int col = ((wn << 1) + g) * 32 + l31;
#pragma unroll
        for (int rg = 0; rg < 4; ++rg) {
            const int d0 = 32 * wm + 8 * rg + 4 * l5;
            float4 xh = *(const float4*)(xhat + b * 128 + d0);
            float4 xx = *(const float4*)(x + b * 128 + d0);
            float v;
            v = zs[g][4*rg+0] + xh.x - xx.x; s = fmaf(v, v, s);
            v = zs[g][4*rg+1] + xh.y - xx.y; s = fmaf(v, v, s);
            v = zs[g][4*rg+2] + xh.z - xx.z; s = fmaf(v, v, s);
            v = zs[g][4*rg+3] + xh.w - xx.w; s = fmaf(v, v, s);
        }
        s += __shfl_xor(s, 32, 64);
        if (l5 == 0) red[wm * 128 + col] = s;
    }
    __syncthreads();
    if (t < 128)
        sdist[t] = red[t] + red[128 + t] + red[256 + t] + red[384 + t];
    __syncthreads();
    int base = 0;
    if (wave == 0) {
        float v0 = sdist[lane], v1 = sdist[lane + 64];
        float m = fminf(v0, v1);
#pragma unroll
        for (int off = 32; off > 0; off >>= 1) m = fminf(m, __shfl_xor(m, off, 64));
        const float thr = m + DELTA;
        const unsigned long long below = (1ull << lane) - 1;
        float vv[2] = {v0, v1};
#pragma unroll
        for (int j = 0; j < 2; ++j) {
            bool p = vv[j] <= thr;
            unsigned long long mask = __ballot(p);
            int pos = base + __popcll(mask & below);
            if (p && pos < 8) sk[pos] = k0 + 64 * j + lane;
            base += __popcll(mask);
        }
    }
    __syncthreads();
    if (t == 0) {
        int c = base > 8 ? 8 : base;
        int off = atomicAdd(npairs, c);
        for (int s = 0; s < c; ++s)
            pairs[off + s] = make_int2(b, sk[s]);
    }
}

// ---------------- exact f32 candidate dists + atomicMin winner ----------------
__global__ __launch_bounds__(256) void k_exact(
    const float* __restrict__ z0, const float* __restrict__ u,
    const float* __restrict__ xhat, const float* __restrict__ x,
    const int2* __restrict__ pairs, const int* __restrict__ npairs,
    const float* __restrict__ W1Ta, const float* __restrict__ W2Ta,
    const float* __restrict__ W1Tb, const float* __restrict__ W2Tb,
    unsigned long long* __restrict__ packed)
{
    __shared__ float z8[8][128];
    __shared__ float h8[8][256];
    __shared__ int pb[8], pk[8];
    __shared__ int scnt;
    __shared__ float part[8][32];
    const int t = threadIdx.x;
    if (t == 0) {
        int np = *npairs; if (np > 32768) np = 32768;
        int c = np - (int)blockIdx.x * 8;
        scnt = c < 0 ? 0 : (c > 8 ? 8 : c);
    }
    __syncthreads();
    const int cnt = scnt;
    if (cnt == 0) return;
    if (t < 8) {
        int idx = blockIdx.x * 8 + (t < cnt ? t : cnt - 1);
        int2 p = pairs[idx];
        pb[t] = p.x; pk[t] = p.y;
    }
    __syncthreads();
#pragma unroll
    for (int n = 0; n < 4; ++n) {
        int e = n * 256 + t; int r = e >> 7, d = e & 127;
        z8[r][d] = z0[pk[r] * 128 + d] + u[pb[r] * 128 + d];
    }
    __syncthreads();
    const float* W1T = W1Ta; const float* W2T = W2Ta;
#pragma unroll 1
    for (int blk = 0; blk < 2; ++blk) {
        float a1[8] = {0.f,0.f,0.f,0.f,0.f,0.f,0.f,0.f};
        for (int d = 0; d < 128; ++d) {
            const float w = W1T[d * 256 + t];
#pragma unroll
            for (int r = 0; r < 8; ++r) a1[r] = fmaf(z8[r][d], w, a1[r]);
        }
#pragma unroll
        for (int r = 0; r < 8; ++r) h8[r][t] = fmaxf(a1[r], 0.f);
        __syncthreads();
        const int ig = t & 127, rg = (t >> 7) * 4;
        float a2[4] = {0.f,0.f,0.f,0.f};
        for (int h = 0; h < 256; ++h) {
            const float w = W2T[h * 128 + ig];
#pragma unroll
            for (int j = 0; j < 4; ++j) a2[j] = fmaf(h8[rg + j][h], w, a2[j]);
        }
        __syncthreads();
#pragma unroll
        for (int j = 0; j < 4; ++j) z8[rg + j][ig] += a2[j];
        __syncthreads();
        W1T = W1Tb; W2T = W2Tb;
    }
    {
        const int r = t >> 5, c = t & 31;
        const int br = pb[r];
        float s = 0.f;
#pragma unroll
        for (int i = 0; i < 4; ++i) {
            int d = c * 4 + i;
            float v = z8[r][d] + xhat[br * 128 + d] - x[br * 128 + d];
            s = fmaf(v, v, s);
        }
        part[r][c] = s;
    }
    __syncthreads();
    if (t < 8 && t < cnt) {
        float s = 0.f;
#pragma unroll
        for (int c2 = 0; c2 < 32; ++c2) s += part[t][c2];
        unsigned long long pk64 = (((unsigned long long)__float_as_uint(s)) << 32)
                                | (unsigned long long)(unsigned)pk[t];
        atomicMin(&packed[pb[t]], pk64);
    }
}

// ---------------- winner recompute + output (f32-exact) ----------------
__global__ __launch_bounds__(256) void k_final(
    const float* __restrict__ z0, const float* __restrict__ u,
    const unsigned long long* __restrict__ packed,
    const float* __restrict__ W1Ta, const float* __restrict__ W2Ta,
    const float* __restrict__ W1Tb, const float* __restrict__ W2Tb,
    float* __restrict__ out0, float* __restrict__ outd)
{
    __shared__ float z8[8][128];
    __shared__ float h8[8][256];
    __shared__ int ci[8];
    const int t = threadIdx.x;
    const int b0 = blockIdx.x * 8;
    if (t < 8) {
        int code = (int)(packed[b0 + t] & 0xFFFFFFFFull);
        ci[t] = code;
        out0[b0 + t] = (float)code;
    }
    __syncthreads();
#pragma unroll
    for (int n = 0; n < 4; ++n) {
        int e = n * 256 + t; int r = e >> 7, d = e & 127;
        z8[r][d] = z0[ci[r] * 128 + d] + u[(b0 + r) * 128 + d];
    }
    __syncthreads();
    const float* W1T = W1Ta; const float* W2T = W2Ta;
#pragma unroll 1
    for (int blk = 0; blk < 2; ++blk) {
        float a1[8] = {0.f,0.f,0.f,0.f,0.f,0.f,0.f,0.f};
        for (int d = 0; d < 128; ++d) {
            const float w = W1T[d * 256 + t];
#pragma unroll
            for (int r = 0; r < 8; ++r) a1[r] = fmaf(z8[r][d], w, a1[r]);
        }
#pragma unroll
        for (int r = 0; r < 8; ++r) h8[r][t] = fmaxf(a1[r], 0.f);
        __syncthreads();
        const int ig = t & 127, rg = (t >> 7) * 4;
        float a2[4] = {0.f,0.f,0.f,0.f};
        for (int h = 0; h < 256; ++h) {
            const float w = W2T[h * 128 + ig];
#pragma unroll
            for (int j = 0; j < 4; ++j) a2[j] = fmaf(h8[rg + j][h], w, a2[j]);
        }
        __syncthreads();
#pragma unroll
        for (int j = 0; j < 4; ++j) z8[rg + j][ig] += a2[j];
        __syncthreads();
        W1T = W1Tb; W2T = W2Tb;
    }
#pragma unroll
    for (int n = 0; n < 4; ++n) {
        int e = n * 256 + t; int r = e >> 7, d = e & 127;
        outd[(b0 + r) * 128 + d] = z8[r][d];
    }
}

extern "C" void kernel_launch(void* const* d_in, const int* in_sizes, int n_in,
                              void* d_out, int out_size, void* d_ws, size_t ws_size,
                              hipStream_t stream) {
    const float* xhat = (const float*)d_in[0];
    const float* x    = (const float*)d_in[1];
    const float* cb   = (const float*)d_in[2];
    const float* Wc   = (const float*)d_in[3];
    const float* bc   = (const float*)d_in[4];
    const float* W1_0 = (const float*)d_in[5];
    const float* W2_0 = (const float*)d_in[6];
    const float* W1_1 = (const float*)d_in[7];
    const float* W2_1 = (const float*)d_in[8];
    float* out = (float*)d_out;
    float* ws  = (float*)d_ws;

    float* WzT   = ws + 0;
    float* WxT   = ws + 16384;
    float* W1T0  = ws + 32768;
    float* W2T0  = ws + 65536;
    float* W1T1  = ws + 98304;
    float* W2T1  = ws + 131072;
    float* z0    = ws + 163840;
    float* u     = ws + 196608;
    float* H1f32 = ws + 458752;
    float* U1    = ws + 524288;
    uint4* F     = (uint4*)(ws + 1048576);
    const uint4* W2f0 = F;
    const uint4* W1f1 = F + 4096;
    const uint4* W2f1 = F + 8192;
    int2*  pairs  = (int2*)(ws + 1097728);
    int*   npairs = (int*)(ws + 1163264);
    unsigned long long* packed = (unsigned long long*)(ws + 1163268);

    k_prep1<<<688, 256, 0, stream>>>(Wc, W1_0, W2_0, W1_1, W2_1,
                                     WzT, WxT, W1T0, W2T0, W1T1, W2T1, F);
    k_prep_k<<<64, 256, 0, stream>>>(cb, bc, WzT, W1T0, z0, H1f32);
    k_prep_b<<<512, 256, 0, stream>>>(xhat, WxT, W1T0, u, U1);
    hipMemsetAsync(npairs, 0, 4, stream);
    hipMemsetAsync(packed, 0xFF, 2048 * 8, stream);
    k_dist_approx<<<4096, 512, 0, stream>>>(z0, u, xhat, x, H1f32, U1,
                                            W2f0, W1f1, W2f1, pairs, npairs);
    k_exact<<<4096, 256, 0, stream>>>(z0, u, xhat, x, pairs, npairs,
                                      W1T0, W2T0, W1T1, W2T1, packed);
    k_final<<<256, 256, 0, stream>>>(z0, u, packed,
                                     W1T0, W2T0, W1T1, W2T1, out, out + 2048);
}